// Round 10
// baseline (356.171 us; speedup 1.0000x reference)
//
#include <hip/hip_runtime.h>
#include <hip/hip_bf16.h>

typedef __bf16 bf16_t;
typedef __bf16 bf16x8 __attribute__((ext_vector_type(8)));
typedef __bf16 bf16x4 __attribute__((ext_vector_type(4)));
typedef float  f32x4  __attribute__((ext_vector_type(4)));

#define S_LEN 4096
#define NH    8
#define DH    64
#define DE    512

// ---------------------------------------------------------------------------
// GEMM tile params (both projection GEMMs)
// ---------------------------------------------------------------------------
#define BM 128
#define BN 128
#define BK 32
#define LDP 40

static __device__ __forceinline__ void stage16_f32(bf16_t* dst, const float* src) {
    const float4 v0 = *reinterpret_cast<const float4*>(src + 0);
    const float4 v1 = *reinterpret_cast<const float4*>(src + 4);
    const float4 v2 = *reinterpret_cast<const float4*>(src + 8);
    const float4 v3 = *reinterpret_cast<const float4*>(src + 12);
    bf16x8 lo, hi;
    lo[0]=(bf16_t)v0.x; lo[1]=(bf16_t)v0.y; lo[2]=(bf16_t)v0.z; lo[3]=(bf16_t)v0.w;
    lo[4]=(bf16_t)v1.x; lo[5]=(bf16_t)v1.y; lo[6]=(bf16_t)v1.z; lo[7]=(bf16_t)v1.w;
    hi[0]=(bf16_t)v2.x; hi[1]=(bf16_t)v2.y; hi[2]=(bf16_t)v2.z; hi[3]=(bf16_t)v2.w;
    hi[4]=(bf16_t)v3.x; hi[5]=(bf16_t)v3.y; hi[6]=(bf16_t)v3.z; hi[7]=(bf16_t)v3.w;
    *reinterpret_cast<bf16x8*>(dst + 0) = lo;
    *reinterpret_cast<bf16x8*>(dst + 8) = hi;
}

// lgkm-only barrier: LDS producer/consumer ordering without draining the
// global-load (vmcnt) queue, so register prefetches survive across phases.
// sched_barrier(0) per guide rule #18 (no reordering across the waitcnt).
static __device__ __forceinline__ void bar_lds() {
    __builtin_amdgcn_sched_barrier(0);
    asm volatile("s_waitcnt lgkmcnt(0)\n\ts_barrier" ::: "memory");
    __builtin_amdgcn_sched_barrier(0);
}

// ---------------------------------------------------------------------------
// Kernel 1: qkv = x @ w_in^T + b_in ; scatter to Q [h][s][64], K [h][s][64],
//           V^T [h][64][s]   (all bf16)
// ---------------------------------------------------------------------------
__global__ __launch_bounds__(256) void qkv_gemm(
    const float* __restrict__ X,
    const float* __restrict__ Win,
    const float* __restrict__ bin,
    bf16_t* __restrict__ qw,
    bf16_t* __restrict__ kw,
    bf16_t* __restrict__ vtw)
{
    __shared__ bf16_t As[BM * LDP];
    __shared__ bf16_t Bs[BN * LDP];

    const int tid  = threadIdx.x;
    const int lane = tid & 63;
    const int w    = tid >> 6;
    const int wr   = w >> 1, wc = w & 1;
    const int row0 = blockIdx.y * BM;
    const int col0 = blockIdx.x * BN;

    const int fr = lane & 15;
    const int fo = (lane >> 4) * 8;
    const int cr = (lane >> 4) * 4;

    const int sr = tid >> 1;
    const int sc = (tid & 1) * 16;

    f32x4 acc[4][4] = {};

    for (int k0 = 0; k0 < DE; k0 += BK) {
        stage16_f32(As + sr * LDP + sc, X   + (row0 + sr) * DE + k0 + sc);
        stage16_f32(Bs + sr * LDP + sc, Win + (col0 + sr) * DE + k0 + sc);
        __syncthreads();

        bf16x8 af[4], bf[4];
        #pragma unroll
        for (int m = 0; m < 4; ++m)
            af[m] = *reinterpret_cast<const bf16x8*>(As + (wr * 64 + m * 16 + fr) * LDP + fo);
        #pragma unroll
        for (int n = 0; n < 4; ++n)
            bf[n] = *reinterpret_cast<const bf16x8*>(Bs + (wc * 64 + n * 16 + fr) * LDP + fo);
        #pragma unroll
        for (int m = 0; m < 4; ++m)
            #pragma unroll
            for (int n = 0; n < 4; ++n)
                acc[m][n] = __builtin_amdgcn_mfma_f32_16x16x32_bf16(af[m], bf[n], acc[m][n], 0, 0, 0);
        __syncthreads();
    }

    #pragma unroll
    for (int m = 0; m < 4; ++m) {
        #pragma unroll
        for (int n = 0; n < 4; ++n) {
            const int col = col0 + wc * 64 + n * 16 + fr;
            const float b = bin[col];
            const int part = col >> 9;
            const int cd   = col & 511;
            const int h    = cd >> 6;
            const int d    = cd & 63;
            #pragma unroll
            for (int r = 0; r < 4; ++r) {
                const int row = row0 + wr * 64 + m * 16 + cr + r;
                const float v = acc[m][n][r] + b;
                const bf16_t bv = (bf16_t)v;
                if (part == 0)      qw [(h * S_LEN + row) * DH + d] = bv;
                else if (part == 1) kw [(h * S_LEN + row) * DH + d] = bv;
                else                vtw[(h * DH + d) * S_LEN + row] = bv;
            }
        }
    }
}

// ---------------------------------------------------------------------------
// Kernel 2: attention, softmax over HEADS axis.  r7 geometry (140 us):
// 512 threads = 8 waves = 8 heads, QT=32, KS=4, 64 KB double-buffered
// e-LDS, 2 blocks/CU.  r10 changes ONLY the latency structure:
//  - bar_lds(): lgkm-only barriers (no vmcnt drain) so global loads float
//    across phases
//  - K-fragments software-pipelined in registers: K(t+1) issued right
//    after QK^T(t)'s e-stores, consumed next iteration (latency hidden
//    under normalize + PV + 2 barriers)
//  - PV loads batched (full unroll)
// Budget: aq 16 + Kpre 32 + PV transients ~48 peak, o 32 acc -> ~115 arch
// regs < 128 cap from __launch_bounds__(512,4).
// ---------------------------------------------------------------------------
template<int QT, int KS>
__global__ __launch_bounds__(512, 4) void attn_kernel(
    const bf16_t* __restrict__ qw,    // [h][s][64]
    const bf16_t* __restrict__ kw,    // [h][s][64]
    const bf16_t* __restrict__ vtw,   // [h][64][s]
    const int*    __restrict__ causal_p,
    bf16_t* __restrict__ part)        // [KS][s][512] partial outputs
{
    constexpr int QF = QT / 16;
    constexpr int NT = (S_LEN / KS) / 64;
    constexpr int KSH = (KS == 4) ? 2 : (KS == 2 ? 1 : 0);

    // [2 buffers][head][q][64 keys], 16B-block XOR swizzle b' = b ^ (q&7)
    __shared__ bf16_t e_lds[2][NH][QT][64];

    const int tid  = threadIdx.x;
    const int lane = tid & 63;
    const int h    = tid >> 6;
    const int kc   = blockIdx.x & (KS - 1);       // key chunk -> XCD-aligned
    const int q0   = (blockIdx.x >> KSH) * QT;
    const int kbase = kc * (S_LEN / KS);
    const int causal = causal_p[0];

    const int fr  = lane & 15;
    const int fog = lane >> 4;
    const int fo  = fog * 8;
    const int cr  = fog * 4;

    // Q fragments (own head): QF row-frags x 2 k-halves (persistent, 16 regs)
    bf16x8 aq[QF][2];
    #pragma unroll
    for (int qf = 0; qf < QF; ++qf) {
        const bf16_t* qb = qw + ((size_t)(h * S_LEN) + q0 + qf * 16 + fr) * DH;
        aq[qf][0] = *reinterpret_cast<const bf16x8*>(qb + fo);
        aq[qf][1] = *reinterpret_cast<const bf16x8*>(qb + 32 + fo);
    }

    f32x4 o[QF][4] = {};   // accumulators (AGPR side of unified file)

    // K software pipeline: current tile's 4 kf-fragments (32 regs)
    bf16x8 kA[4], kB[4];
    {
        #pragma unroll
        for (int kf = 0; kf < 4; ++kf) {
            const bf16_t* kb = kw + ((size_t)(h * S_LEN) + kbase + kf * 16 + fr) * DH;
            kA[kf] = *reinterpret_cast<const bf16x8*>(kb + fo);
            kB[kf] = *reinterpret_cast<const bf16x8*>(kb + 32 + fo);
        }
    }

    #pragma unroll 1
    for (int t = 0; t < NT; ++t) {
        const int kg = kbase + t * 64;
        bf16_t* wbuf = &e_lds[t & 1][h][0][0];

        // ---- QK^T + exp from register K-frags -> e-stores ----
        #pragma unroll
        for (int kf = 0; kf < 4; ++kf) {
            #pragma unroll
            for (int qf = 0; qf < QF; ++qf) {
                f32x4 z = {};
                z = __builtin_amdgcn_mfma_f32_16x16x32_bf16(aq[qf][0], kA[kf], z, 0, 0, 0);
                z = __builtin_amdgcn_mfma_f32_16x16x32_bf16(aq[qf][1], kB[kf], z, 0, 0, 0);
                #pragma unroll
                for (int r = 0; r < 4; ++r) {
                    float val = __expf(z[r] * 0.125f);
                    if (causal) {
                        if (kg + kf * 16 + fr > q0 + qf * 16 + cr + r) val = 0.f;
                    }
                    const int q = qf * 16 + cr + r;
                    const int k = kf * 16 + fr;
                    const int bp = (k >> 3) ^ (q & 7);
                    wbuf[q * 64 + bp * 8 + (k & 7)] = (bf16_t)val;
                }
            }
        }

        // ---- issue K(t+1) loads: latency hides under norm + PV + barriers
        if (t + 1 < NT) {
            const int kn = kg + 64;
            #pragma unroll
            for (int kf = 0; kf < 4; ++kf) {
                const bf16_t* kb = kw + ((size_t)(h * S_LEN) + kn + kf * 16 + fr) * DH;
                kA[kf] = *reinterpret_cast<const bf16x8*>(kb + fo);
                kB[kf] = *reinterpret_cast<const bf16x8*>(kb + 32 + fo);
            }
        }

        bar_lds();   // e(t) visible (lgkm only; K-prefetch stays in flight)

        // ---- cross-head normalize in place, 2-pass (r7 verbatim) ----
        if (tid < QT * 16) {
            const int q  = tid >> 4;
            const int hb = tid & 15;
            const int bp = (hb >> 1) ^ (q & 7);
            bf16_t* base = &e_lds[t & 1][0][0][0] + q * 64 + bp * 8 + (hb & 1) * 4;

            float den0 = 0.f, den1 = 0.f, den2 = 0.f, den3 = 0.f;
            #pragma unroll
            for (int hh = 0; hh < NH; ++hh) {
                const bf16x4 v = *reinterpret_cast<const bf16x4*>(base + hh * (QT * 64));
                den0 += (float)v[0]; den1 += (float)v[1];
                den2 += (float)v[2]; den3 += (float)v[3];
            }
            const float rd0 = (den0 > 0.f) ? __builtin_amdgcn_rcpf(den0) : 0.f;
            const float rd1 = (den1 > 0.f) ? __builtin_amdgcn_rcpf(den1) : 0.f;
            const float rd2 = (den2 > 0.f) ? __builtin_amdgcn_rcpf(den2) : 0.f;
            const float rd3 = (den3 > 0.f) ? __builtin_amdgcn_rcpf(den3) : 0.f;
            #pragma unroll
            for (int hh = 0; hh < NH; ++hh) {
                bf16_t* p = base + hh * (QT * 64);
                const bf16x4 v = *reinterpret_cast<const bf16x4*>(p);
                bf16x4 wv;
                wv[0] = (bf16_t)((float)v[0] * rd0);
                wv[1] = (bf16_t)((float)v[1] * rd1);
                wv[2] = (bf16_t)((float)v[2] * rd2);
                wv[3] = (bf16_t)((float)v[3] * rd3);
                *reinterpret_cast<bf16x4*>(p) = wv;
            }
        }
        bar_lds();   // w(t) ready

        // ---- PV(t): batched pa + V loads, then 16 MFMAs ----
        {
            bf16x8 pa[2][QF];
            #pragma unroll
            for (int c = 0; c < 2; ++c)
                #pragma unroll
                for (int qf = 0; qf < QF; ++qf) {
                    const int q  = qf * 16 + fr;
                    const int bp = (4 * c + fog) ^ (q & 7);
                    pa[c][qf] = *reinterpret_cast<const bf16x8*>(wbuf + q * 64 + bp * 8);
                }
            #pragma unroll
            for (int c = 0; c < 2; ++c)
                #pragma unroll
                for (int n = 0; n < 4; ++n) {
                    const bf16x8 vvn = *reinterpret_cast<const bf16x8*>(
                        vtw + ((size_t)(h * DH + n * 16 + fr)) * S_LEN + kg + c * 32 + fo);
                    #pragma unroll
                    for (int qf = 0; qf < QF; ++qf)
                        o[qf][n] = __builtin_amdgcn_mfma_f32_16x16x32_bf16(pa[c][qf], vvn, o[qf][n], 0, 0, 0);
                }
        }
        // next tile writes the other buffer; 2 barriers/tile total
    }

    // write partial output tile [QT][512] bf16
    bf16_t* pp = part + (size_t)kc * (S_LEN * DE);
    #pragma unroll
    for (int qf = 0; qf < QF; ++qf)
        #pragma unroll
        for (int n = 0; n < 4; ++n)
            #pragma unroll
            for (int r = 0; r < 4; ++r)
                pp[(size_t)(q0 + qf * 16 + cr + r) * DE + h * 64 + n * 16 + fr] =
                    (bf16_t)o[qf][n][r];
}

// ---------------------------------------------------------------------------
// Kernel 3: out = (sum_kc part_kc) @ w_out^T + b_out   (f32 output)
// ---------------------------------------------------------------------------
template<int KS>
__global__ __launch_bounds__(256) void out_gemm(
    const bf16_t* __restrict__ part,   // [KS][4096][512] bf16
    const float*  __restrict__ Wout,
    const float*  __restrict__ bout,
    float* __restrict__ out)
{
    __shared__ bf16_t As[BM * LDP];
    __shared__ bf16_t Bs[BN * LDP];

    const int tid  = threadIdx.x;
    const int lane = tid & 63;
    const int w    = tid >> 6;
    const int wr   = w >> 1, wc = w & 1;
    const int row0 = blockIdx.y * BM;
    const int col0 = blockIdx.x * BN;

    const int fr = lane & 15;
    const int fo = (lane >> 4) * 8;
    const int cr = (lane >> 4) * 4;

    const int sr = tid >> 1;
    const int sc = (tid & 1) * 16;

    f32x4 acc[4][4] = {};

    for (int k0 = 0; k0 < DE; k0 += BK) {
        // A staging: sum KS partials (bf16 -> f32 add -> bf16)
        {
            const size_t off = (size_t)(row0 + sr) * DE + k0 + sc;
            #pragma unroll
            for (int v = 0; v < 2; ++v) {
                bf16x8 a = *reinterpret_cast<const bf16x8*>(part + off + v * 8);
                #pragma unroll
                for (int p = 1; p < KS; ++p) {
                    bf16x8 b = *reinterpret_cast<const bf16x8*>(
                        part + (size_t)p * (S_LEN * DE) + off + v * 8);
                    #pragma unroll
                    for (int j = 0; j < 8; ++j)
                        a[j] = (bf16_t)((float)a[j] + (float)b[j]);
                }
                *reinterpret_cast<bf16x8*>(As + sr * LDP + sc + v * 8) = a;
            }
        }
        stage16_f32(Bs + sr * LDP + sc, Wout + (col0 + sr) * DE + k0 + sc);
        __syncthreads();

        bf16x8 af[4], bf[4];
        #pragma unroll
        for (int m = 0; m < 4; ++m)
            af[m] = *reinterpret_cast<const bf16x8*>(As + (wr * 64 + m * 16 + fr) * LDP + fo);
        #pragma unroll
        for (int n = 0; n < 4; ++n)
            bf[n] = *reinterpret_cast<const bf16x8*>(Bs + (wc * 64 + n * 16 + fr) * LDP + fo);
        #pragma unroll
        for (int m = 0; m < 4; ++m)
            #pragma unroll
            for (int n = 0; n < 4; ++n)
                acc[m][n] = __builtin_amdgcn_mfma_f32_16x16x32_bf16(af[m], bf[n], acc[m][n], 0, 0, 0);
        __syncthreads();
    }

    #pragma unroll
    for (int m = 0; m < 4; ++m) {
        #pragma unroll
        for (int n = 0; n < 4; ++n) {
            const int col = col0 + wc * 64 + n * 16 + fr;
            const float b = bout[col];
            #pragma unroll
            for (int r = 0; r < 4; ++r) {
                const int row = row0 + wr * 64 + m * 16 + cr + r;
                out[row * DE + col] = acc[m][n][r] + b;
            }
        }
    }
}

// ---------------------------------------------------------------------------
// Launch: pick key-split factor by available workspace.
//   needs (3 + KS) * 4 MiB of d_ws.
// ---------------------------------------------------------------------------
extern "C" void kernel_launch(void* const* d_in, const int* in_sizes, int n_in,
                              void* d_out, int out_size, void* d_ws, size_t ws_size,
                              hipStream_t stream) {
    const float* x     = (const float*)d_in[0];
    const float* w_in  = (const float*)d_in[1];
    const float* b_in  = (const float*)d_in[2];
    const float* w_out = (const float*)d_in[3];
    const float* b_out = (const float*)d_in[4];
    const int*   causal = (const int*)d_in[5];
    float* out = (float*)d_out;

    const size_t segE = (size_t)NH * S_LEN * DH;      // 2M bf16 elems = 4 MiB
    bf16_t* qw   = (bf16_t*)d_ws;
    bf16_t* kw   = qw  + segE;
    bf16_t* vtw  = kw  + segE;
    bf16_t* part = vtw + segE;

    dim3 g1(3 * DE / BN, S_LEN / BM);   // (12, 32)
    qkv_gemm<<<g1, 256, 0, stream>>>(x, w_in, b_in, qw, kw, vtw);

    dim3 g3(DE / BN, S_LEN / BM);       // (4, 32)

    const size_t segB = segE * sizeof(bf16_t);        // 4 MiB
    if (ws_size >= 7 * segB) {
        // QT=32, KS=4: grid = 4 * 128 = 512 blocks -> 2 blocks/CU
        attn_kernel<32, 4><<<512, 512, 0, stream>>>(qw, kw, vtw, causal, part);
        out_gemm<4><<<g3, 256, 0, stream>>>(part, w_out, b_out, out);
    } else if (ws_size >= 5 * segB) {
        attn_kernel<32, 2><<<256, 512, 0, stream>>>(qw, kw, vtw, causal, part);
        out_gemm<2><<<g3, 256, 0, stream>>>(part, w_out, b_out, out);
    } else {
        attn_kernel<16, 1><<<256, 512, 0, stream>>>(qw, kw, vtw, causal, part);
        out_gemm<1><<<g3, 256, 0, stream>>>(part, w_out, b_out, out);
    }
}

// Round 11
// 212.556 us; speedup vs baseline: 1.6757x; 1.6757x over previous
//
#include <hip/hip_runtime.h>
#include <hip/hip_bf16.h>

typedef __bf16 bf16_t;
typedef __bf16 bf16x8 __attribute__((ext_vector_type(8)));
typedef __bf16 bf16x4 __attribute__((ext_vector_type(4)));
typedef float  f32x4  __attribute__((ext_vector_type(4)));

#define S_LEN 4096
#define NH    8
#define DH    64
#define DE    512

// ---------------------------------------------------------------------------
// GEMM tile params (both projection GEMMs)
// ---------------------------------------------------------------------------
#define BM 128
#define BN 128
#define BK 32
#define LDP 40

static __device__ __forceinline__ void stage16_f32(bf16_t* dst, const float* src) {
    const float4 v0 = *reinterpret_cast<const float4*>(src + 0);
    const float4 v1 = *reinterpret_cast<const float4*>(src + 4);
    const float4 v2 = *reinterpret_cast<const float4*>(src + 8);
    const float4 v3 = *reinterpret_cast<const float4*>(src + 12);
    bf16x8 lo, hi;
    lo[0]=(bf16_t)v0.x; lo[1]=(bf16_t)v0.y; lo[2]=(bf16_t)v0.z; lo[3]=(bf16_t)v0.w;
    lo[4]=(bf16_t)v1.x; lo[5]=(bf16_t)v1.y; lo[6]=(bf16_t)v1.z; lo[7]=(bf16_t)v1.w;
    hi[0]=(bf16_t)v2.x; hi[1]=(bf16_t)v2.y; hi[2]=(bf16_t)v2.z; hi[3]=(bf16_t)v2.w;
    hi[4]=(bf16_t)v3.x; hi[5]=(bf16_t)v3.y; hi[6]=(bf16_t)v3.z; hi[7]=(bf16_t)v3.w;
    *reinterpret_cast<bf16x8*>(dst + 0) = lo;
    *reinterpret_cast<bf16x8*>(dst + 8) = hi;
}

// ---------------------------------------------------------------------------
// Kernel 1: qkv = x @ w_in^T + b_in ; scatter to Q [h][s][64], K [h][s][64],
//           V^T [h][64][s]   (all bf16)
// ---------------------------------------------------------------------------
__global__ __launch_bounds__(256) void qkv_gemm(
    const float* __restrict__ X,
    const float* __restrict__ Win,
    const float* __restrict__ bin,
    bf16_t* __restrict__ qw,
    bf16_t* __restrict__ kw,
    bf16_t* __restrict__ vtw)
{
    __shared__ bf16_t As[BM * LDP];
    __shared__ bf16_t Bs[BN * LDP];

    const int tid  = threadIdx.x;
    const int lane = tid & 63;
    const int w    = tid >> 6;
    const int wr   = w >> 1, wc = w & 1;
    const int row0 = blockIdx.y * BM;
    const int col0 = blockIdx.x * BN;

    const int fr = lane & 15;
    const int fo = (lane >> 4) * 8;
    const int cr = (lane >> 4) * 4;

    const int sr = tid >> 1;
    const int sc = (tid & 1) * 16;

    f32x4 acc[4][4] = {};

    for (int k0 = 0; k0 < DE; k0 += BK) {
        stage16_f32(As + sr * LDP + sc, X   + (row0 + sr) * DE + k0 + sc);
        stage16_f32(Bs + sr * LDP + sc, Win + (col0 + sr) * DE + k0 + sc);
        __syncthreads();

        bf16x8 af[4], bf[4];
        #pragma unroll
        for (int m = 0; m < 4; ++m)
            af[m] = *reinterpret_cast<const bf16x8*>(As + (wr * 64 + m * 16 + fr) * LDP + fo);
        #pragma unroll
        for (int n = 0; n < 4; ++n)
            bf[n] = *reinterpret_cast<const bf16x8*>(Bs + (wc * 64 + n * 16 + fr) * LDP + fo);
        #pragma unroll
        for (int m = 0; m < 4; ++m)
            #pragma unroll
            for (int n = 0; n < 4; ++n)
                acc[m][n] = __builtin_amdgcn_mfma_f32_16x16x32_bf16(af[m], bf[n], acc[m][n], 0, 0, 0);
        __syncthreads();
    }

    #pragma unroll
    for (int m = 0; m < 4; ++m) {
        #pragma unroll
        for (int n = 0; n < 4; ++n) {
            const int col = col0 + wc * 64 + n * 16 + fr;
            const float b = bin[col];
            const int part = col >> 9;
            const int cd   = col & 511;
            const int h    = cd >> 6;
            const int d    = cd & 63;
            #pragma unroll
            for (int r = 0; r < 4; ++r) {
                const int row = row0 + wr * 64 + m * 16 + cr + r;
                const float v = acc[m][n][r] + b;
                const bf16_t bv = (bf16_t)v;
                if (part == 0)      qw [(h * S_LEN + row) * DH + d] = bv;
                else if (part == 1) kw [(h * S_LEN + row) * DH + d] = bv;
                else                vtw[(h * DH + d) * S_LEN + row] = bv;
            }
        }
    }
}

// ---------------------------------------------------------------------------
// Kernel 2: attention, softmax over HEADS axis.  r7 kernel body verbatim
// (the only structure that runs spill-free at the backend's hard 64-VGPR
// allocation: unroll-1 kf/c loops, 2-pass normalize, JIT pa/vv loads).
//
// r10 post-mortem: any >64-live-reg structure spills (r3/r6/r10 all
// confirmed); register prefetch is off the table. Remaining lever = TLP.
// NB template selects e-LDS buffering:
//   NB=2 (64 KB): r7 exact — 2 barriers/tile, 2 blocks/CU.
//   NB=1 (32 KB): 3 barriers/tile but 4 blocks/CU = 32 waves/CU when the
//     grid supplies 4 blocks/CU (KS=8 -> grid 1024 = 256 CU x 4).
// KS=8 also makes kc = blockIdx&7 = XCD id -> each XCD's K+V slice is
// 1 MB, fully L2-resident.
// ---------------------------------------------------------------------------
template<int QT, int KS, int NB>
__global__ __launch_bounds__(512, 4) void attn_kernel(
    const bf16_t* __restrict__ qw,    // [h][s][64]
    const bf16_t* __restrict__ kw,    // [h][s][64]
    const bf16_t* __restrict__ vtw,   // [h][64][s]
    const int*    __restrict__ causal_p,
    bf16_t* __restrict__ part)        // [KS][s][512] partial outputs
{
    constexpr int QF = QT / 16;
    constexpr int NT = (S_LEN / KS) / 64;
    constexpr int KSH = (KS == 8) ? 3 : (KS == 4) ? 2 : (KS == 2) ? 1 : 0;

    // [NB buffers][head][q][64 keys], 16B-block XOR swizzle b' = b ^ (q&7)
    __shared__ bf16_t e_lds[NB][NH][QT][64];

    const int tid  = threadIdx.x;
    const int lane = tid & 63;
    const int h    = tid >> 6;
    const int kc   = blockIdx.x & (KS - 1);       // key chunk == XCD id (KS=8)
    const int q0   = (blockIdx.x >> KSH) * QT;
    const int kbase = kc * (S_LEN / KS);
    const int causal = causal_p[0];

    const int fr  = lane & 15;
    const int fog = lane >> 4;
    const int fo  = fog * 8;
    const int cr  = fog * 4;

    // Q fragments (own head): QF row-frags x 2 k-halves (persistent, 16 regs)
    bf16x8 aq[QF][2];
    #pragma unroll
    for (int qf = 0; qf < QF; ++qf) {
        const bf16_t* qb = qw + ((size_t)(h * S_LEN) + q0 + qf * 16 + fr) * DH;
        aq[qf][0] = *reinterpret_cast<const bf16x8*>(qb + fo);
        aq[qf][1] = *reinterpret_cast<const bf16x8*>(qb + 32 + fo);
    }

    f32x4 o[QF][4] = {};   // accumulators (AGPR side of unified file)

    for (int t = 0; t < NT; ++t) {
        const int kg = kbase + t * 64;
        const int bidx = (NB == 2) ? (t & 1) : 0;
        bf16_t* wbuf = &e_lds[bidx][h][0][0];

        // ---- QK^T + exp -> write e(t) ----
        // unroll 1: keep only one kf's K-fragments (8 regs) live at a time
        #pragma unroll 1
        for (int kf = 0; kf < 4; ++kf) {
            const bf16_t* kb = kw + ((size_t)(h * S_LEN) + kg + kf * 16 + fr) * DH;
            const bf16x8 b0 = *reinterpret_cast<const bf16x8*>(kb + fo);
            const bf16x8 b1 = *reinterpret_cast<const bf16x8*>(kb + 32 + fo);
            #pragma unroll
            for (int qf = 0; qf < QF; ++qf) {
                f32x4 z = {};
                z = __builtin_amdgcn_mfma_f32_16x16x32_bf16(aq[qf][0], b0, z, 0, 0, 0);
                z = __builtin_amdgcn_mfma_f32_16x16x32_bf16(aq[qf][1], b1, z, 0, 0, 0);
                #pragma unroll
                for (int r = 0; r < 4; ++r) {
                    float val = __expf(z[r] * 0.125f);
                    if (causal) {
                        if (kg + kf * 16 + fr > q0 + qf * 16 + cr + r) val = 0.f;
                    }
                    const int q = qf * 16 + cr + r;
                    const int k = kf * 16 + fr;
                    const int bp = (k >> 3) ^ (q & 7);
                    wbuf[q * 64 + bp * 8 + (k & 7)] = (bf16_t)val;
                }
            }
        }

        __syncthreads();   // all e(t) writes visible

        // ---- cross-head normalize in place, 2-pass (no eh[] array) ----
        if (tid < QT * 16) {
            const int q  = tid >> 4;
            const int hb = tid & 15;
            const int bp = (hb >> 1) ^ (q & 7);
            bf16_t* base = &e_lds[bidx][0][0][0] + q * 64 + bp * 8 + (hb & 1) * 4;

            float den0 = 0.f, den1 = 0.f, den2 = 0.f, den3 = 0.f;
            #pragma unroll
            for (int hh = 0; hh < NH; ++hh) {
                const bf16x4 v = *reinterpret_cast<const bf16x4*>(base + hh * (QT * 64));
                den0 += (float)v[0]; den1 += (float)v[1];
                den2 += (float)v[2]; den3 += (float)v[3];
            }
            const float rd0 = (den0 > 0.f) ? __builtin_amdgcn_rcpf(den0) : 0.f;
            const float rd1 = (den1 > 0.f) ? __builtin_amdgcn_rcpf(den1) : 0.f;
            const float rd2 = (den2 > 0.f) ? __builtin_amdgcn_rcpf(den2) : 0.f;
            const float rd3 = (den3 > 0.f) ? __builtin_amdgcn_rcpf(den3) : 0.f;
            #pragma unroll
            for (int hh = 0; hh < NH; ++hh) {
                bf16_t* p = base + hh * (QT * 64);
                const bf16x4 v = *reinterpret_cast<const bf16x4*>(p);
                bf16x4 wv;
                wv[0] = (bf16_t)((float)v[0] * rd0);
                wv[1] = (bf16_t)((float)v[1] * rd1);
                wv[2] = (bf16_t)((float)v[2] * rd2);
                wv[3] = (bf16_t)((float)v[3] * rd3);
                *reinterpret_cast<bf16x4*>(p) = wv;
            }
        }
        __syncthreads();   // w(t) ready

        // ---- PV(t): o += w(t) @ V(t); pa/vv loaded just-in-time ----
        #pragma unroll 1
        for (int c = 0; c < 2; ++c) {
            bf16x8 pa[QF];
            #pragma unroll
            for (int qf = 0; qf < QF; ++qf) {
                const int q  = qf * 16 + fr;
                const int bp = (4 * c + fog) ^ (q & 7);
                pa[qf] = *reinterpret_cast<const bf16x8*>(wbuf + q * 64 + bp * 8);
            }
            #pragma unroll
            for (int n = 0; n < 4; ++n) {
                const bf16x8 vvn = *reinterpret_cast<const bf16x8*>(
                    vtw + ((size_t)(h * DH + n * 16 + fr)) * S_LEN + kg + c * 32 + fo);
                #pragma unroll
                for (int qf = 0; qf < QF; ++qf)
                    o[qf][n] = __builtin_amdgcn_mfma_f32_16x16x32_bf16(pa[qf], vvn, o[qf][n], 0, 0, 0);
            }
        }

        if (NB == 1) __syncthreads();   // single buffer: PV done before overwrite
        // NB==2: next tile writes the other buffer; no extra barrier needed
    }

    // write partial output tile [QT][512] bf16
    bf16_t* pp = part + (size_t)kc * (S_LEN * DE);
    #pragma unroll
    for (int qf = 0; qf < QF; ++qf)
        #pragma unroll
        for (int n = 0; n < 4; ++n)
            #pragma unroll
            for (int r = 0; r < 4; ++r)
                pp[(size_t)(q0 + qf * 16 + cr + r) * DE + h * 64 + n * 16 + fr] =
                    (bf16_t)o[qf][n][r];
}

// ---------------------------------------------------------------------------
// Kernel 3: out = (sum_kc part_kc) @ w_out^T + b_out   (f32 output)
// ---------------------------------------------------------------------------
template<int KS>
__global__ __launch_bounds__(256) void out_gemm(
    const bf16_t* __restrict__ part,   // [KS][4096][512] bf16
    const float*  __restrict__ Wout,
    const float*  __restrict__ bout,
    float* __restrict__ out)
{
    __shared__ bf16_t As[BM * LDP];
    __shared__ bf16_t Bs[BN * LDP];

    const int tid  = threadIdx.x;
    const int lane = tid & 63;
    const int w    = tid >> 6;
    const int wr   = w >> 1, wc = w & 1;
    const int row0 = blockIdx.y * BM;
    const int col0 = blockIdx.x * BN;

    const int fr = lane & 15;
    const int fo = (lane >> 4) * 8;
    const int cr = (lane >> 4) * 4;

    const int sr = tid >> 1;
    const int sc = (tid & 1) * 16;

    f32x4 acc[4][4] = {};

    for (int k0 = 0; k0 < DE; k0 += BK) {
        // A staging: sum KS partials (bf16 -> f32 add -> bf16)
        {
            const size_t off = (size_t)(row0 + sr) * DE + k0 + sc;
            #pragma unroll
            for (int v = 0; v < 2; ++v) {
                bf16x8 a = *reinterpret_cast<const bf16x8*>(part + off + v * 8);
                #pragma unroll
                for (int p = 1; p < KS; ++p) {
                    bf16x8 b = *reinterpret_cast<const bf16x8*>(
                        part + (size_t)p * (S_LEN * DE) + off + v * 8);
                    #pragma unroll
                    for (int j = 0; j < 8; ++j)
                        a[j] = (bf16_t)((float)a[j] + (float)b[j]);
                }
                *reinterpret_cast<bf16x8*>(As + sr * LDP + sc + v * 8) = a;
            }
        }
        stage16_f32(Bs + sr * LDP + sc, Wout + (col0 + sr) * DE + k0 + sc);
        __syncthreads();

        bf16x8 af[4], bf[4];
        #pragma unroll
        for (int m = 0; m < 4; ++m)
            af[m] = *reinterpret_cast<const bf16x8*>(As + (wr * 64 + m * 16 + fr) * LDP + fo);
        #pragma unroll
        for (int n = 0; n < 4; ++n)
            bf[n] = *reinterpret_cast<const bf16x8*>(Bs + (wc * 64 + n * 16 + fr) * LDP + fo);
        #pragma unroll
        for (int m = 0; m < 4; ++m)
            #pragma unroll
            for (int n = 0; n < 4; ++n)
                acc[m][n] = __builtin_amdgcn_mfma_f32_16x16x32_bf16(af[m], bf[n], acc[m][n], 0, 0, 0);
        __syncthreads();
    }

    #pragma unroll
    for (int m = 0; m < 4; ++m) {
        #pragma unroll
        for (int n = 0; n < 4; ++n) {
            const int col = col0 + wc * 64 + n * 16 + fr;
            const float b = bout[col];
            #pragma unroll
            for (int r = 0; r < 4; ++r) {
                const int row = row0 + wr * 64 + m * 16 + cr + r;
                out[row * DE + col] = acc[m][n][r] + b;
            }
        }
    }
}

// ---------------------------------------------------------------------------
// Launch: pick key-split factor by available workspace.
//   needs (3 + KS) * 4 MiB of d_ws.
// ---------------------------------------------------------------------------
extern "C" void kernel_launch(void* const* d_in, const int* in_sizes, int n_in,
                              void* d_out, int out_size, void* d_ws, size_t ws_size,
                              hipStream_t stream) {
    const float* x     = (const float*)d_in[0];
    const float* w_in  = (const float*)d_in[1];
    const float* b_in  = (const float*)d_in[2];
    const float* w_out = (const float*)d_in[3];
    const float* b_out = (const float*)d_in[4];
    const int*   causal = (const int*)d_in[5];
    float* out = (float*)d_out;

    const size_t segE = (size_t)NH * S_LEN * DH;      // 2M bf16 elems = 4 MiB
    bf16_t* qw   = (bf16_t*)d_ws;
    bf16_t* kw   = qw  + segE;
    bf16_t* vtw  = kw  + segE;
    bf16_t* part = vtw + segE;

    dim3 g1(3 * DE / BN, S_LEN / BM);   // (12, 32)
    qkv_gemm<<<g1, 256, 0, stream>>>(x, w_in, b_in, qw, kw, vtw);

    dim3 g3(DE / BN, S_LEN / BM);       // (4, 32)

    const size_t segB = segE * sizeof(bf16_t);        // 4 MiB
    if (ws_size >= 11 * segB) {
        // QT=32, KS=8, single-buffer LDS: grid = 8*128 = 1024 = 4 blocks/CU
        attn_kernel<32, 8, 1><<<1024, 512, 0, stream>>>(qw, kw, vtw, causal, part);
        out_gemm<8><<<g3, 256, 0, stream>>>(part, w_out, b_out, out);
    } else if (ws_size >= 7 * segB) {
        // r7 exact fallback: QT=32, KS=4, double-buffer, 2 blocks/CU
        attn_kernel<32, 4, 2><<<512, 512, 0, stream>>>(qw, kw, vtw, causal, part);
        out_gemm<4><<<g3, 256, 0, stream>>>(part, w_out, b_out, out);
    } else if (ws_size >= 5 * segB) {
        attn_kernel<32, 2, 2><<<256, 512, 0, stream>>>(qw, kw, vtw, causal, part);
        out_gemm<2><<<g3, 256, 0, stream>>>(part, w_out, b_out, out);
    } else {
        attn_kernel<16, 1, 2><<<256, 512, 0, stream>>>(qw, kw, vtw, causal, part);
        out_gemm<1><<<g3, 256, 0, stream>>>(part, w_out, b_out, out);
    }
}

// Round 12
// 199.594 us; speedup vs baseline: 1.7845x; 1.0649x over previous
//
#include <hip/hip_runtime.h>
#include <hip/hip_bf16.h>

typedef __bf16 bf16_t;
typedef __bf16 bf16x8 __attribute__((ext_vector_type(8)));
typedef __bf16 bf16x4 __attribute__((ext_vector_type(4)));
typedef float  f32x4  __attribute__((ext_vector_type(4)));

#define S_LEN 4096
#define NH    8
#define DH    64
#define DE    512

// ---------------------------------------------------------------------------
// GEMM tile params (both projection GEMMs)
// ---------------------------------------------------------------------------
#define BM 128
#define BN 128
#define BK 32
#define LDP 40

static __device__ __forceinline__ void stage16_f32(bf16_t* dst, const float* src) {
    const float4 v0 = *reinterpret_cast<const float4*>(src + 0);
    const float4 v1 = *reinterpret_cast<const float4*>(src + 4);
    const float4 v2 = *reinterpret_cast<const float4*>(src + 8);
    const float4 v3 = *reinterpret_cast<const float4*>(src + 12);
    bf16x8 lo, hi;
    lo[0]=(bf16_t)v0.x; lo[1]=(bf16_t)v0.y; lo[2]=(bf16_t)v0.z; lo[3]=(bf16_t)v0.w;
    lo[4]=(bf16_t)v1.x; lo[5]=(bf16_t)v1.y; lo[6]=(bf16_t)v1.z; lo[7]=(bf16_t)v1.w;
    hi[0]=(bf16_t)v2.x; hi[1]=(bf16_t)v2.y; hi[2]=(bf16_t)v2.z; hi[3]=(bf16_t)v2.w;
    hi[4]=(bf16_t)v3.x; hi[5]=(bf16_t)v3.y; hi[6]=(bf16_t)v3.z; hi[7]=(bf16_t)v3.w;
    *reinterpret_cast<bf16x8*>(dst + 0) = lo;
    *reinterpret_cast<bf16x8*>(dst + 8) = hi;
}

// ---------------------------------------------------------------------------
// Kernel 1: qkv = x @ w_in^T + b_in ; scatter to Q [h][s][64], K [h][s][64],
//           V^T [h][64][s]   (all bf16)
// ---------------------------------------------------------------------------
__global__ __launch_bounds__(256) void qkv_gemm(
    const float* __restrict__ X,
    const float* __restrict__ Win,
    const float* __restrict__ bin,
    bf16_t* __restrict__ qw,
    bf16_t* __restrict__ kw,
    bf16_t* __restrict__ vtw)
{
    __shared__ bf16_t As[BM * LDP];
    __shared__ bf16_t Bs[BN * LDP];

    const int tid  = threadIdx.x;
    const int lane = tid & 63;
    const int w    = tid >> 6;
    const int wr   = w >> 1, wc = w & 1;
    const int row0 = blockIdx.y * BM;
    const int col0 = blockIdx.x * BN;

    const int fr = lane & 15;
    const int fo = (lane >> 4) * 8;
    const int cr = (lane >> 4) * 4;

    const int sr = tid >> 1;
    const int sc = (tid & 1) * 16;

    f32x4 acc[4][4] = {};

    for (int k0 = 0; k0 < DE; k0 += BK) {
        stage16_f32(As + sr * LDP + sc, X   + (row0 + sr) * DE + k0 + sc);
        stage16_f32(Bs + sr * LDP + sc, Win + (col0 + sr) * DE + k0 + sc);
        __syncthreads();

        bf16x8 af[4], bf[4];
        #pragma unroll
        for (int m = 0; m < 4; ++m)
            af[m] = *reinterpret_cast<const bf16x8*>(As + (wr * 64 + m * 16 + fr) * LDP + fo);
        #pragma unroll
        for (int n = 0; n < 4; ++n)
            bf[n] = *reinterpret_cast<const bf16x8*>(Bs + (wc * 64 + n * 16 + fr) * LDP + fo);
        #pragma unroll
        for (int m = 0; m < 4; ++m)
            #pragma unroll
            for (int n = 0; n < 4; ++n)
                acc[m][n] = __builtin_amdgcn_mfma_f32_16x16x32_bf16(af[m], bf[n], acc[m][n], 0, 0, 0);
        __syncthreads();
    }

    #pragma unroll
    for (int m = 0; m < 4; ++m) {
        #pragma unroll
        for (int n = 0; n < 4; ++n) {
            const int col = col0 + wc * 64 + n * 16 + fr;
            const float b = bin[col];
            const int part = col >> 9;
            const int cd   = col & 511;
            const int h    = cd >> 6;
            const int d    = cd & 63;
            #pragma unroll
            for (int r = 0; r < 4; ++r) {
                const int row = row0 + wr * 64 + m * 16 + cr + r;
                const float v = acc[m][n][r] + b;
                const bf16_t bv = (bf16_t)v;
                if (part == 0)      qw [(h * S_LEN + row) * DH + d] = bv;
                else if (part == 1) kw [(h * S_LEN + row) * DH + d] = bv;
                else                vtw[(h * DH + d) * S_LEN + row] = bv;
            }
        }
    }
}

// ---------------------------------------------------------------------------
// Kernel 2: attention, softmax over HEADS axis.
// 512 threads = 8 waves = 8 heads, QT queries, KS-way key split; r7's
// spill-free register discipline (64-arch-VGPR hard cap: unroll-1 loops,
// 2-pass normalize, JIT loads).
//
// r12 structural changes at FIXED occupancy (~45% is the ceiling: 64 arch
// + 64 acc = 128 unified regs/wave -> 4 waves/SIMD):
//  - 128-key phases, single 64 KB e-buffer: 3 barriers/128 keys vs r7's 4.
//  - transposed QK^T (mfma(K,Q), validated r8/r9): D[row=k, col=q] ->
//    lane holds 4 consecutive k at fixed q -> ONE b64 e-store per (kf,qf)
//    vs 16 scalar b16 stores (-75% store insts).
// LDS layout [h][q][128k], 16B-block swizzle p' = p ^ (q&15): e-store
// 2-way (free), PV b128 reads 8-bank-spread, normalize b128 per head.
// ---------------------------------------------------------------------------
template<int QT, int KS>
__global__ __launch_bounds__(512, 4) void attn_kernel(
    const bf16_t* __restrict__ qw,    // [h][s][64]
    const bf16_t* __restrict__ kw,    // [h][s][64]
    const bf16_t* __restrict__ vtw,   // [h][64][s]
    const int*    __restrict__ causal_p,
    bf16_t* __restrict__ part)        // [KS][s][512] partial outputs
{
    constexpr int QF = QT / 16;
    constexpr int KT = 128;                    // keys per phase
    constexpr int NT = (S_LEN / KS) / KT;
    constexpr int KSH = (KS == 8) ? 3 : (KS == 4) ? 2 : (KS == 2) ? 1 : 0;

    __shared__ bf16_t e_lds[NH][QT][KT];       // 64 KB at QT=32

    const int tid  = threadIdx.x;
    const int lane = tid & 63;
    const int h    = tid >> 6;                 // wave = head
    const int kc   = blockIdx.x & (KS - 1);    // key chunk
    const int q0   = (blockIdx.x >> KSH) * QT;
    const int kbase = kc * (S_LEN / KS);
    const int causal = causal_p[0];

    const int fr  = lane & 15;
    const int fog = lane >> 4;
    const int fo  = fog * 8;
    const int cr  = fog * 4;

    // Q fragments: lane fr holds Q[q0+qf*16+fr][d]. Works as the B-operand
    // of the transposed QK^T (col=q) AND matches PV's A-operand data flow.
    bf16x8 aq[QF][2];
    #pragma unroll
    for (int qf = 0; qf < QF; ++qf) {
        const bf16_t* qb = qw + ((size_t)(h * S_LEN) + q0 + qf * 16 + fr) * DH;
        aq[qf][0] = *reinterpret_cast<const bf16x8*>(qb + fo);
        aq[qf][1] = *reinterpret_cast<const bf16x8*>(qb + 32 + fo);
    }

    f32x4 o[QF][4] = {};   // accumulators (AGPR side)

    for (int t = 0; t < NT; ++t) {
        const int kg = kbase + t * KT;
        bf16_t* ebuf = &e_lds[h][0][0];

        // ---- transposed QK^T + exp: z = mfma(K,Q) -> D[k_local][q];
        //      one b64 e-store per (kf, qf). unroll 1 keeps 1 kfrag live.
        #pragma unroll 1
        for (int kf = 0; kf < KT / 16; ++kf) {
            const bf16_t* kb = kw + ((size_t)(h * S_LEN) + kg + kf * 16 + fr) * DH;
            const bf16x8 k0v = *reinterpret_cast<const bf16x8*>(kb + fo);
            const bf16x8 k1v = *reinterpret_cast<const bf16x8*>(kb + 32 + fo);
            #pragma unroll
            for (int qf = 0; qf < QF; ++qf) {
                f32x4 z = {};
                z = __builtin_amdgcn_mfma_f32_16x16x32_bf16(k0v, aq[qf][0], z, 0, 0, 0);
                z = __builtin_amdgcn_mfma_f32_16x16x32_bf16(k1v, aq[qf][1], z, 0, 0, 0);
                bf16x4 ev;
                #pragma unroll
                for (int r = 0; r < 4; ++r) {
                    float val = __expf(z[r] * 0.125f);
                    if (causal) {
                        if (kg + kf * 16 + cr + r > q0 + qf * 16 + fr) val = 0.f;
                    }
                    ev[r] = (bf16_t)val;
                }
                const int q = qf * 16 + fr;
                const int p = (kf * 2 + (fog >> 1)) ^ (q & 15);
                *reinterpret_cast<bf16x4*>(ebuf + q * KT + p * 8 + (fog & 1) * 4) = ev;
            }
        }

        __syncthreads();   // e(t) visible

        // ---- cross-head normalize in place, 2-pass, b128 per head ----
        if (tid < QT * 16) {
            const int q = tid >> 4;
            const int j = tid & 15;                  // 16B block index
            const int p = j ^ (q & 15);
            bf16_t* base = &e_lds[0][0][0] + q * KT + p * 8;
            float den[8] = {};
            #pragma unroll
            for (int hh = 0; hh < NH; ++hh) {
                const bf16x8 v = *reinterpret_cast<const bf16x8*>(base + hh * (QT * KT));
                #pragma unroll
                for (int i = 0; i < 8; ++i) den[i] += (float)v[i];
            }
            float rd[8];
            #pragma unroll
            for (int i = 0; i < 8; ++i)
                rd[i] = (den[i] > 0.f) ? __builtin_amdgcn_rcpf(den[i]) : 0.f;
            #pragma unroll
            for (int hh = 0; hh < NH; ++hh) {
                bf16_t* pp = base + hh * (QT * KT);
                const bf16x8 v = *reinterpret_cast<const bf16x8*>(pp);
                bf16x8 wv;
                #pragma unroll
                for (int i = 0; i < 8; ++i) wv[i] = (bf16_t)((float)v[i] * rd[i]);
                *reinterpret_cast<bf16x8*>(pp) = wv;
            }
        }
        __syncthreads();   // w(t) ready

        // ---- PV(t): o += w(t) @ V(t); pa/vv loaded just-in-time ----
        #pragma unroll 1
        for (int c = 0; c < KT / 32; ++c) {
            bf16x8 pa[QF];
            #pragma unroll
            for (int qf = 0; qf < QF; ++qf) {
                const int q = qf * 16 + fr;
                const int p = (c * 4 + fog) ^ (q & 15);
                pa[qf] = *reinterpret_cast<const bf16x8*>(ebuf + q * KT + p * 8);
            }
            #pragma unroll
            for (int n = 0; n < 4; ++n) {
                const bf16x8 vvn = *reinterpret_cast<const bf16x8*>(
                    vtw + ((size_t)(h * DH + n * 16 + fr)) * S_LEN + kg + c * 32 + fo);
                #pragma unroll
                for (int qf = 0; qf < QF; ++qf)
                    o[qf][n] = __builtin_amdgcn_mfma_f32_16x16x32_bf16(pa[qf], vvn, o[qf][n], 0, 0, 0);
            }
        }

        __syncthreads();   // PV done before next phase overwrites ebuf
    }

    // write partial output tile [QT][512] bf16
    bf16_t* pp = part + (size_t)kc * (S_LEN * DE);
    #pragma unroll
    for (int qf = 0; qf < QF; ++qf)
        #pragma unroll
        for (int n = 0; n < 4; ++n)
            #pragma unroll
            for (int r = 0; r < 4; ++r)
                pp[(size_t)(q0 + qf * 16 + cr + r) * DE + h * 64 + n * 16 + fr] =
                    (bf16_t)o[qf][n][r];
}

// ---------------------------------------------------------------------------
// Kernel 3: out = (sum_kc part_kc) @ w_out^T + b_out   (f32 output)
// ---------------------------------------------------------------------------
template<int KS>
__global__ __launch_bounds__(256) void out_gemm(
    const bf16_t* __restrict__ part,   // [KS][4096][512] bf16
    const float*  __restrict__ Wout,
    const float*  __restrict__ bout,
    float* __restrict__ out)
{
    __shared__ bf16_t As[BM * LDP];
    __shared__ bf16_t Bs[BN * LDP];

    const int tid  = threadIdx.x;
    const int lane = tid & 63;
    const int w    = tid >> 6;
    const int wr   = w >> 1, wc = w & 1;
    const int row0 = blockIdx.y * BM;
    const int col0 = blockIdx.x * BN;

    const int fr = lane & 15;
    const int fo = (lane >> 4) * 8;
    const int cr = (lane >> 4) * 4;

    const int sr = tid >> 1;
    const int sc = (tid & 1) * 16;

    f32x4 acc[4][4] = {};

    for (int k0 = 0; k0 < DE; k0 += BK) {
        // A staging: sum KS partials (bf16 -> f32 add -> bf16)
        {
            const size_t off = (size_t)(row0 + sr) * DE + k0 + sc;
            #pragma unroll
            for (int v = 0; v < 2; ++v) {
                bf16x8 a = *reinterpret_cast<const bf16x8*>(part + off + v * 8);
                #pragma unroll
                for (int p = 1; p < KS; ++p) {
                    bf16x8 b = *reinterpret_cast<const bf16x8*>(
                        part + (size_t)p * (S_LEN * DE) + off + v * 8);
                    #pragma unroll
                    for (int j = 0; j < 8; ++j)
                        a[j] = (bf16_t)((float)a[j] + (float)b[j]);
                }
                *reinterpret_cast<bf16x8*>(As + sr * LDP + sc + v * 8) = a;
            }
        }
        stage16_f32(Bs + sr * LDP + sc, Wout + (col0 + sr) * DE + k0 + sc);
        __syncthreads();

        bf16x8 af[4], bf[4];
        #pragma unroll
        for (int m = 0; m < 4; ++m)
            af[m] = *reinterpret_cast<const bf16x8*>(As + (wr * 64 + m * 16 + fr) * LDP + fo);
        #pragma unroll
        for (int n = 0; n < 4; ++n)
            bf[n] = *reinterpret_cast<const bf16x8*>(Bs + (wc * 64 + n * 16 + fr) * LDP + fo);
        #pragma unroll
        for (int m = 0; m < 4; ++m)
            #pragma unroll
            for (int n = 0; n < 4; ++n)
                acc[m][n] = __builtin_amdgcn_mfma_f32_16x16x32_bf16(af[m], bf[n], acc[m][n], 0, 0, 0);
        __syncthreads();
    }

    #pragma unroll
    for (int m = 0; m < 4; ++m) {
        #pragma unroll
        for (int n = 0; n < 4; ++n) {
            const int col = col0 + wc * 64 + n * 16 + fr;
            const float b = bout[col];
            #pragma unroll
            for (int r = 0; r < 4; ++r) {
                const int row = row0 + wr * 64 + m * 16 + cr + r;
                out[row * DE + col] = acc[m][n][r] + b;
            }
        }
    }
}

// ---------------------------------------------------------------------------
// Launch: pick key-split factor by available workspace.
//   needs (3 + KS) * 4 MiB of d_ws.
// ---------------------------------------------------------------------------
extern "C" void kernel_launch(void* const* d_in, const int* in_sizes, int n_in,
                              void* d_out, int out_size, void* d_ws, size_t ws_size,
                              hipStream_t stream) {
    const float* x     = (const float*)d_in[0];
    const float* w_in  = (const float*)d_in[1];
    const float* b_in  = (const float*)d_in[2];
    const float* w_out = (const float*)d_in[3];
    const float* b_out = (const float*)d_in[4];
    const int*   causal = (const int*)d_in[5];
    float* out = (float*)d_out;

    const size_t segE = (size_t)NH * S_LEN * DH;      // 2M bf16 elems = 4 MiB
    bf16_t* qw   = (bf16_t*)d_ws;
    bf16_t* kw   = qw  + segE;
    bf16_t* vtw  = kw  + segE;
    bf16_t* part = vtw + segE;

    dim3 g1(3 * DE / BN, S_LEN / BM);   // (12, 32)
    qkv_gemm<<<g1, 256, 0, stream>>>(x, w_in, b_in, qw, kw, vtw);

    dim3 g3(DE / BN, S_LEN / BM);       // (4, 32)

    const size_t segB = segE * sizeof(bf16_t);        // 4 MiB
    if (ws_size >= 7 * segB) {
        // QT=32, KS=4: grid = 4 * 128 = 512 blocks -> 2 blocks/CU
        attn_kernel<32, 4><<<512, 512, 0, stream>>>(qw, kw, vtw, causal, part);
        out_gemm<4><<<g3, 256, 0, stream>>>(part, w_out, b_out, out);
    } else if (ws_size >= 5 * segB) {
        attn_kernel<32, 2><<<256, 512, 0, stream>>>(qw, kw, vtw, causal, part);
        out_gemm<2><<<g3, 256, 0, stream>>>(part, w_out, b_out, out);
    } else {
        attn_kernel<16, 1><<<128, 512, 0, stream>>>(qw, kw, vtw, causal, part);
        out_gemm<1><<<g3, 256, 0, stream>>>(part, w_out, b_out, out);
    }
}